// Round 2
// baseline (710.785 us; speedup 1.0000x reference)
//
#include <hip/hip_runtime.h>
#include <cstddef>

#define NN 100
#define TT 256
#define BB 128
#define SS 7
#define FF 35
#define GG 16

__constant__ int c_off[5] = {0, -10, 1, 10, -1};

__device__ __forceinline__ float sigmoidf_(float v) {
  return 1.0f / (1.0f + __expf(-v));
}
__device__ __forceinline__ float tanhf_(float v) {
  return 1.0f - 2.0f / (__expf(2.0f * v) + 1.0f);
}

// ---------------- K1: lm layer 1: H1[b][n][h] = relu(xl @ W1 + b1) ----------------
__global__ void __launch_bounds__(512)
k_lm1(const float* __restrict__ x, const float* __restrict__ W1,
      const float* __restrict__ b1, float* __restrict__ H1) {
  const int bc = blockIdx.x;   // 0..3 (chunk of 32 b)
  const int n  = blockIdx.y;   // 0..99
  const int b0 = bc * 32;
  const int tid = threadIdx.x;
  __shared__ __align__(16) float xl[32][36];
  for (int idx = tid; idx < 32 * FF; idx += 512) {
    const int bb = idx / FF, f = idx % FF;
    const int m = n + c_off[f / SS];
    const int s = f % SS;
    float v = 0.0f;
    if (m >= 0 && m < NN)
      v = x[(((size_t)(b0 + bb) * TT + (TT - 1)) * NN + m) * SS + s];
    xl[bb][f] = v;
  }
  __syncthreads();
  const int h = tid;           // 512 columns
  float w[FF];
  const float* wp = W1 + (size_t)n * FF * 512 + h;
#pragma unroll
  for (int f = 0; f < FF; ++f) w[f] = wp[(size_t)f * 512];
  const float bias = b1[n * 512 + h];
  for (int bb = 0; bb < 32; ++bb) {
    const float4* xr = (const float4*)(&xl[bb][0]);
    float acc = bias;
#pragma unroll
    for (int q = 0; q < 8; ++q) {
      const float4 v = xr[q];
      acc += w[4*q+0] * v.x + w[4*q+1] * v.y + w[4*q+2] * v.z + w[4*q+3] * v.w;
    }
    {
      const float4 v = xr[8];
      acc += w[32] * v.x + w[33] * v.y + w[34] * v.z;
    }
    H1[((size_t)(b0 + bb) * NN + n) * 512 + h] = fmaxf(acc, 0.0f);
  }
}

// ---------------- K2: lm layer 2: H2 = relu(H1 @ W2 + b2), per-n GEMM ----------------
__global__ void __launch_bounds__(256)
k_lm2(const float* __restrict__ H1, const float* __restrict__ W2,
      const float* __restrict__ b2, float* __restrict__ H2) {
  const int n  = blockIdx.x;        // 0..99
  const int bh = blockIdx.y >> 1;   // 0..1 (64 rows each)
  const int ch = blockIdx.y & 1;    // 0..1 (128 cols each)
  const int tid = threadIdx.x;
  const int tc = tid & 15;
  const int tb = tid >> 4;
  __shared__ __align__(16) float A[32][68];    // [k][b]
  __shared__ __align__(16) float Bt[32][132];  // [k][c]
  float acc[4][8];
#pragma unroll
  for (int i = 0; i < 4; ++i)
#pragma unroll
    for (int j = 0; j < 8; ++j) acc[i][j] = 0.0f;

  for (int k0 = 0; k0 < 512; k0 += 32) {
    __syncthreads();
    for (int l = tid; l < 512; l += 256) {          // A: 64b x 32k
      const int bi = l >> 3, kq = l & 7;
      const float4 v = *(const float4*)(&H1[((size_t)(bh*64 + bi) * NN + n) * 512 + k0 + kq*4]);
      A[kq*4+0][bi] = v.x; A[kq*4+1][bi] = v.y; A[kq*4+2][bi] = v.z; A[kq*4+3][bi] = v.w;
    }
    for (int l = tid; l < 1024; l += 256) {         // Bt: 32k x 128c
      const int kk = l >> 5, c4 = l & 31;
      const float4 v = *(const float4*)(&W2[((size_t)n * 512 + (k0 + kk)) * 256 + ch*128 + c4*4]);
      *(float4*)(&Bt[kk][c4*4]) = v;
    }
    __syncthreads();
#pragma unroll 4
    for (int k = 0; k < 32; ++k) {
      const float4 a4 = *(const float4*)(&A[k][tb*4]);
      const float4 p0 = *(const float4*)(&Bt[k][tc*8]);
      const float4 p1 = *(const float4*)(&Bt[k][tc*8 + 4]);
      const float av[4] = {a4.x, a4.y, a4.z, a4.w};
      const float bv[8] = {p0.x, p0.y, p0.z, p0.w, p1.x, p1.y, p1.z, p1.w};
#pragma unroll
      for (int i = 0; i < 4; ++i)
#pragma unroll
        for (int j = 0; j < 8; ++j) acc[i][j] += av[i] * bv[j];
    }
  }
#pragma unroll
  for (int i = 0; i < 4; ++i) {
    const int b = bh*64 + tb*4 + i;
    const int c0 = ch*128 + tc*8;
    const float* bp = b2 + n*256 + c0;
    float4 o0, o1;
    o0.x = fmaxf(acc[i][0] + bp[0], 0.0f);
    o0.y = fmaxf(acc[i][1] + bp[1], 0.0f);
    o0.z = fmaxf(acc[i][2] + bp[2], 0.0f);
    o0.w = fmaxf(acc[i][3] + bp[3], 0.0f);
    o1.x = fmaxf(acc[i][4] + bp[4], 0.0f);
    o1.y = fmaxf(acc[i][5] + bp[5], 0.0f);
    o1.z = fmaxf(acc[i][6] + bp[6], 0.0f);
    o1.w = fmaxf(acc[i][7] + bp[7], 0.0f);
    float* op = H2 + ((size_t)b * NN + n) * 256 + c0;
    *(float4*)(op) = o0;
    *(float4*)(op + 4) = o1;
  }
}

// ---------------- K3: lm layer 3: out[n*B+b] = H2 . W3 + b3 ----------------
__global__ void __launch_bounds__(256)
k_lm3(const float* __restrict__ H2, const float* __restrict__ W3,
      const float* __restrict__ b3, float* __restrict__ out) {
  const int w = threadIdx.x >> 6;
  const int lane = threadIdx.x & 63;
  const int p = blockIdx.x * 4 + w;   // 0..12799
  const int b = p / NN, n = p % NN;
  const float4 hv = *(const float4*)(&H2[((size_t)b * NN + n) * 256 + lane*4]);
  const float4 wv = *(const float4*)(&W3[n * 256 + lane*4]);
  float dot = hv.x*wv.x + hv.y*wv.y + hv.z*wv.z + hv.w*wv.w;
#pragma unroll
  for (int off = 32; off > 0; off >>= 1) dot += __shfl_down(dot, off);
  if (lane == 0) out[n * BB + b] = dot + b3[n];
}

// ---------------- K4: fused GRU over T + sc head, out += q ----------------
__global__ void __launch_bounds__(256, 2)
k_gru(const float* __restrict__ x,
      const float* __restrict__ Wih, const float* __restrict__ Whh,
      const float* __restrict__ bih, const float* __restrict__ bhh,
      const float* __restrict__ sW1, const float* __restrict__ sb1,
      const float* __restrict__ sW2, const float* __restrict__ sb2,
      const float* __restrict__ sW3, const float* __restrict__ sb3,
      float* __restrict__ out) {
  const int bc = blockIdx.x;   // 0..7 (chunk of 16 b)
  const int n  = blockIdx.y;   // 0..99
  const int b0 = bc * 16;
  const int tid = threadIdx.x;
  const int bl = tid >> 4;     // 0..15 local batch
  const int g  = tid & 15;     // 0..15 hidden unit

  __shared__ __align__(16) float xt[2][16][36];
  __shared__ __align__(16) float hbuf[16][16];

  // per-thread weight registers: rows g, 16+g, 32+g
  float wr[FF], wz[FF], wn_[FF];
  {
    const float* p = Wih + (size_t)n * 48 * FF;
#pragma unroll
    for (int f = 0; f < FF; ++f) {
      wr[f]  = p[(g)      * FF + f];
      wz[f]  = p[(16 + g) * FF + f];
      wn_[f] = p[(32 + g) * FF + f];
    }
  }
  float ur[GG], uz[GG], un[GG];
  {
    const float* p = Whh + (size_t)n * 48 * GG;
#pragma unroll
    for (int k = 0; k < GG; ++k) {
      ur[k] = p[(g)      * GG + k];
      uz[k] = p[(16 + g) * GG + k];
      un[k] = p[(32 + g) * GG + k];
    }
  }
  const float bir = bih[n*48 + g], biz = bih[n*48 + 16 + g], bin_ = bih[n*48 + 32 + g];
  const float bhr = bhh[n*48 + g], bhz = bhh[n*48 + 16 + g], bhn = bhh[n*48 + 32 + g];

  hbuf[bl][g] = 0.0f;
  // stage xt for t = 0 (16*35 = 560 values)
  for (int idx = tid; idx < 16 * FF; idx += 256) {
    const int bb = idx / FF, f = idx % FF;
    const int m = n + c_off[f / SS], s = f % SS;
    float v = 0.0f;
    if (m >= 0 && m < NN)
      v = x[(((size_t)(b0 + bb) * TT + 0) * NN + m) * SS + s];
    xt[0][bb][f] = v;
  }
  __syncthreads();

  // precomputed gather coordinates for the two staging slots per thread
  const int i0 = tid, i1 = tid + 256;
  const int bb0 = i0 / FF, f0 = i0 % FF;
  const int m0 = n + c_off[f0 / SS], s0 = f0 % SS;
  const bool v0ok = (m0 >= 0 && m0 < NN);
  const bool use1 = (i1 < 16 * FF);
  const int bb1 = use1 ? i1 / FF : 0, f1 = use1 ? i1 % FF : 0;
  const int m1 = n + c_off[f1 / SS], s1 = f1 % SS;
  const bool v1ok = use1 && (m1 >= 0 && m1 < NN);
  const size_t xbase0 = ((size_t)(b0 + bb0) * TT) * NN * SS + (size_t)((m0 >= 0 && m0 < NN) ? m0 : 0) * SS + s0;
  const size_t xbase1 = ((size_t)(b0 + bb1) * TT) * NN * SS + (size_t)((m1 >= 0 && m1 < NN) ? m1 : 0) * SS + s1;

  float hown = 0.0f;
  for (int t = 0; t < TT; ++t) {
    const int cur = t & 1;
    float pf0 = 0.0f, pf1 = 0.0f;
    if (t + 1 < TT) {
      if (v0ok) pf0 = x[xbase0 + (size_t)(t + 1) * NN * SS];
      if (v1ok) pf1 = x[xbase1 + (size_t)(t + 1) * NN * SS];
    }
    // gi = Wih @ xt + bih (rows g, 16+g, 32+g)
    float ar = bir, az = biz, an = bin_;
    const float4* xr = (const float4*)(&xt[cur][bl][0]);
#pragma unroll
    for (int q = 0; q < 8; ++q) {
      const float4 v = xr[q];
      ar += wr[4*q+0]*v.x + wr[4*q+1]*v.y + wr[4*q+2]*v.z + wr[4*q+3]*v.w;
      az += wz[4*q+0]*v.x + wz[4*q+1]*v.y + wz[4*q+2]*v.z + wz[4*q+3]*v.w;
      an += wn_[4*q+0]*v.x + wn_[4*q+1]*v.y + wn_[4*q+2]*v.z + wn_[4*q+3]*v.w;
    }
    {
      const float4 v = xr[8];
      ar += wr[32]*v.x + wr[33]*v.y + wr[34]*v.z;
      az += wz[32]*v.x + wz[33]*v.y + wz[34]*v.z;
      an += wn_[32]*v.x + wn_[33]*v.y + wn_[34]*v.z;
    }
    // gh = Whh @ h + bhh
    float hr_ = bhr, hz_ = bhz, hn_ = bhn;
    {
      const float4* hv4 = (const float4*)(&hbuf[bl][0]);
#pragma unroll
      for (int q = 0; q < 4; ++q) {
        const float4 v = hv4[q];
        hr_ += ur[4*q+0]*v.x + ur[4*q+1]*v.y + ur[4*q+2]*v.z + ur[4*q+3]*v.w;
        hz_ += uz[4*q+0]*v.x + uz[4*q+1]*v.y + uz[4*q+2]*v.z + uz[4*q+3]*v.w;
        hn_ += un[4*q+0]*v.x + un[4*q+1]*v.y + un[4*q+2]*v.z + un[4*q+3]*v.w;
      }
    }
    const float r  = sigmoidf_(ar + hr_);
    const float z  = sigmoidf_(az + hz_);
    const float nn2 = tanhf_(an + r * hn_);
    const float hnew = (1.0f - z) * nn2 + z * hown;
    __syncthreads();                 // all reads of hbuf / xt[cur] complete
    hbuf[bl][g] = hnew;
    hown = hnew;
    if (t + 1 < TT) {
      xt[cur ^ 1][bb0][f0] = pf0;
      if (use1) xt[cur ^ 1][bb1][f1] = pf1;
    }
    __syncthreads();                 // writes visible for next step
  }

  // ----- sc head: 16 -> 16 -> 16 -> 1 -----
  float a1 = sb1[n*GG + g];
  {
    const float4* hv4 = (const float4*)(&hbuf[bl][0]);
    const float* w = sW1 + n*GG*GG;
#pragma unroll
    for (int q = 0; q < 4; ++q) {
      const float4 v = hv4[q];
      a1 += v.x*w[(4*q+0)*GG + g] + v.y*w[(4*q+1)*GG + g]
          + v.z*w[(4*q+2)*GG + g] + v.w*w[(4*q+3)*GG + g];
    }
  }
  a1 = fmaxf(a1, 0.0f);
  __syncthreads();
  hbuf[bl][g] = a1;
  __syncthreads();
  float a2 = sb2[n*GG + g];
  {
    const float4* hv4 = (const float4*)(&hbuf[bl][0]);
    const float* w = sW2 + n*GG*GG;
#pragma unroll
    for (int q = 0; q < 4; ++q) {
      const float4 v = hv4[q];
      a2 += v.x*w[(4*q+0)*GG + g] + v.y*w[(4*q+1)*GG + g]
          + v.z*w[(4*q+2)*GG + g] + v.w*w[(4*q+3)*GG + g];
    }
  }
  a2 = fmaxf(a2, 0.0f);
  __syncthreads();
  hbuf[bl][g] = a2;
  __syncthreads();
  if (g == 0) {
    const float4* hv4 = (const float4*)(&hbuf[bl][0]);
    const float* w = sW3 + n*GG;
    float qv = sb3[n];
#pragma unroll
    for (int qq = 0; qq < 4; ++qq) {
      const float4 v = hv4[qq];
      qv += v.x*w[4*qq+0] + v.y*w[4*qq+1] + v.z*w[4*qq+2] + v.w*w[4*qq+3];
    }
    out[n * BB + (b0 + bl)] += qv;   // adds onto f written by k_lm3
  }
}

extern "C" void kernel_launch(void* const* d_in, const int* in_sizes, int n_in,
                              void* d_out, int out_size, void* d_ws, size_t ws_size,
                              hipStream_t stream) {
  const float* x     = (const float*)d_in[0];
  const float* lm_W1 = (const float*)d_in[1];
  const float* lm_b1 = (const float*)d_in[2];
  const float* lm_W2 = (const float*)d_in[3];
  const float* lm_b2 = (const float*)d_in[4];
  const float* lm_W3 = (const float*)d_in[5];
  const float* lm_b3 = (const float*)d_in[6];
  const float* gWih  = (const float*)d_in[7];
  const float* gWhh  = (const float*)d_in[8];
  const float* gbih  = (const float*)d_in[9];
  const float* gbhh  = (const float*)d_in[10];
  const float* sW1   = (const float*)d_in[11];
  const float* sb1   = (const float*)d_in[12];
  const float* sW2   = (const float*)d_in[13];
  const float* sb2   = (const float*)d_in[14];
  const float* sW3   = (const float*)d_in[15];
  const float* sb3   = (const float*)d_in[16];
  float* out = (float*)d_out;

  float* H1 = (float*)d_ws;                                       // 128*100*512 f32 = 26.2 MB
  float* H2 = (float*)((char*)d_ws + (size_t)BB * NN * 512 * 4);  // 128*100*256 f32 = 13.1 MB

  k_lm1<<<dim3(4, NN), 512, 0, stream>>>(x, lm_W1, lm_b1, H1);
  k_lm2<<<dim3(NN, 4), 256, 0, stream>>>(H1, lm_W2, lm_b2, H2);
  k_lm3<<<dim3(3200), 256, 0, stream>>>(H2, lm_W3, lm_b3, out);
  k_gru<<<dim3(8, NN), 256, 0, stream>>>(x, gWih, gWhh, gbih, gbhh,
                                         sW1, sb1, sW2, sb2, sW3, sb3, out);
}

// Round 4
// 539.764 us; speedup vs baseline: 1.3168x; 1.3168x over previous
//
#include <hip/hip_runtime.h>
#include <cstddef>

#define NN 100
#define TT 256
#define BB 128
#define SS 7
#define FF 35
#define GG 16

typedef __attribute__((ext_vector_type(4))) float f32x4;
typedef __attribute__((ext_vector_type(8))) short short8;

__constant__ int c_off[5] = {0, -10, 1, 10, -1};

__device__ __forceinline__ float sigmoidf_(float v) {
  return 1.0f / (1.0f + __expf(-v));
}
__device__ __forceinline__ float tanhf_(float v) {
  return 1.0f - 2.0f / (__expf(2.0f * v) + 1.0f);
}
__device__ __forceinline__ unsigned bf1(float a) {
  unsigned u = __float_as_uint(a);
  return (u + 0x7FFFu + ((u >> 16) & 1u)) >> 16;
}
__device__ __forceinline__ unsigned bfp(float lo, float hi) {
  return bf1(lo) | (bf1(hi) << 16);
}

// ---------------- K1: lm layer 1: H1[b][n][h] = relu(xl @ W1 + b1) ----------------
__global__ void __launch_bounds__(512)
k_lm1(const float* __restrict__ x, const float* __restrict__ W1,
      const float* __restrict__ b1, float* __restrict__ H1) {
  const int bc = blockIdx.x;   // 0..3 (chunk of 32 b)
  const int n  = blockIdx.y;   // 0..99
  const int b0 = bc * 32;
  const int tid = threadIdx.x;
  __shared__ __align__(16) float xl[32][36];
  for (int idx = tid; idx < 32 * FF; idx += 512) {
    const int bb = idx / FF, f = idx % FF;
    const int m = n + c_off[f / SS];
    const int s = f % SS;
    float v = 0.0f;
    if (m >= 0 && m < NN)
      v = x[(((size_t)(b0 + bb) * TT + (TT - 1)) * NN + m) * SS + s];
    xl[bb][f] = v;
  }
  __syncthreads();
  const int h = tid;           // 512 columns
  float w[FF];
  const float* wp = W1 + (size_t)n * FF * 512 + h;
#pragma unroll
  for (int f = 0; f < FF; ++f) w[f] = wp[(size_t)f * 512];
  const float bias = b1[n * 512 + h];
  for (int bb = 0; bb < 32; ++bb) {
    const float4* xr = (const float4*)(&xl[bb][0]);
    float acc = bias;
#pragma unroll
    for (int q = 0; q < 8; ++q) {
      const float4 v = xr[q];
      acc += w[4*q+0] * v.x + w[4*q+1] * v.y + w[4*q+2] * v.z + w[4*q+3] * v.w;
    }
    {
      const float4 v = xr[8];
      acc += w[32] * v.x + w[33] * v.y + w[34] * v.z;
    }
    H1[((size_t)(b0 + bb) * NN + n) * 512 + h] = fmaxf(acc, 0.0f);
  }
}

// ---------------- K2: lm layer 2: H2 = relu(H1 @ W2 + b2), per-n GEMM 64x64 tiles ----------------
__global__ void __launch_bounds__(256)
k_lm2(const float* __restrict__ H1, const float* __restrict__ W2,
      const float* __restrict__ b2, float* __restrict__ H2) {
  const int n  = blockIdx.x;        // 0..99
  const int bh = blockIdx.y >> 2;   // 0..1 (64 rows each)
  const int ch = blockIdx.y & 3;    // 0..3 (64 cols each)
  const int tid = threadIdx.x;
  const int tc = tid & 15;
  const int tb = tid >> 4;
  __shared__ __align__(16) float A[32][68];    // [k][b]
  __shared__ __align__(16) float Bt[32][68];   // [k][c]
  float acc[4][4];
#pragma unroll
  for (int i = 0; i < 4; ++i)
#pragma unroll
    for (int j = 0; j < 4; ++j) acc[i][j] = 0.0f;

  for (int k0 = 0; k0 < 512; k0 += 32) {
    __syncthreads();
    for (int l = tid; l < 512; l += 256) {          // A: 64b x 32k
      const int bi = l >> 3, kq = l & 7;
      const float4 v = *(const float4*)(&H1[((size_t)(bh*64 + bi) * NN + n) * 512 + k0 + kq*4]);
      A[kq*4+0][bi] = v.x; A[kq*4+1][bi] = v.y; A[kq*4+2][bi] = v.z; A[kq*4+3][bi] = v.w;
    }
    for (int l = tid; l < 512; l += 256) {          // Bt: 32k x 64c
      const int kk = l >> 4, c4 = l & 15;
      const float4 v = *(const float4*)(&W2[((size_t)n * 512 + (k0 + kk)) * 256 + ch*64 + c4*4]);
      *(float4*)(&Bt[kk][c4*4]) = v;
    }
    __syncthreads();
#pragma unroll 8
    for (int k = 0; k < 32; ++k) {
      const float4 a4 = *(const float4*)(&A[k][tb*4]);
      const float4 b4 = *(const float4*)(&Bt[k][tc*4]);
      const float av[4] = {a4.x, a4.y, a4.z, a4.w};
      const float bv[4] = {b4.x, b4.y, b4.z, b4.w};
#pragma unroll
      for (int i = 0; i < 4; ++i)
#pragma unroll
        for (int j = 0; j < 4; ++j) acc[i][j] += av[i] * bv[j];
    }
  }
#pragma unroll
  for (int i = 0; i < 4; ++i) {
    const int b = bh*64 + tb*4 + i;
    const int c0 = ch*64 + tc*4;
    const float* bp = b2 + n*256 + c0;
    float4 o;
    o.x = fmaxf(acc[i][0] + bp[0], 0.0f);
    o.y = fmaxf(acc[i][1] + bp[1], 0.0f);
    o.z = fmaxf(acc[i][2] + bp[2], 0.0f);
    o.w = fmaxf(acc[i][3] + bp[3], 0.0f);
    *(float4*)(&H2[((size_t)b * NN + n) * 256 + c0]) = o;
  }
}

// ---------------- K3: lm layer 3: out[n*B+b] = H2 . W3 + b3 ----------------
__global__ void __launch_bounds__(256)
k_lm3(const float* __restrict__ H2, const float* __restrict__ W3,
      const float* __restrict__ b3, float* __restrict__ out) {
  const int w = threadIdx.x >> 6;
  const int lane = threadIdx.x & 63;
  const int p = blockIdx.x * 4 + w;   // 0..12799
  const int b = p / NN, n = p % NN;
  const float4 hv = *(const float4*)(&H2[((size_t)b * NN + n) * 256 + lane*4]);
  const float4 wv = *(const float4*)(&W3[n * 256 + lane*4]);
  float dot = hv.x*wv.x + hv.y*wv.y + hv.z*wv.z + hv.w*wv.w;
#pragma unroll
  for (int off = 32; off > 0; off >>= 1) dot += __shfl_down(dot, off);
  if (lane == 0) out[n * BB + b] = dot + b3[n];
}

#define DOT16(acc, u0, u1, u2, u3, h0, h1, h2, h3)             \
  acc += u0.x*h0.x + u0.y*h0.y + u0.z*h0.z + u0.w*h0.w;        \
  acc += u1.x*h1.x + u1.y*h1.y + u1.z*h1.z + u1.w*h1.w;        \
  acc += u2.x*h2.x + u2.y*h2.y + u2.z*h2.z + u2.w*h2.w;        \
  acc += u3.x*h3.x + u3.y*h3.y + u3.z*h3.z + u3.w*h3.w;

// ---------------- K4: fused GRU (MFMA gi) + sc head; 1 wave per (n, 4 batches) ----------------
__global__ void __launch_bounds__(64, 3)
k_gru(const float* __restrict__ x,
      const float* __restrict__ Wih, const float* __restrict__ Whh,
      const float* __restrict__ bih, const float* __restrict__ bhh,
      const float* __restrict__ sW1, const float* __restrict__ sb1,
      const float* __restrict__ sW2, const float* __restrict__ sb2,
      const float* __restrict__ sW3, const float* __restrict__ sb3,
      float* __restrict__ out) {
  const int l  = threadIdx.x;       // 0..63
  const int g  = l & 15;            // hidden unit (pointwise/gh) ; also B col
  const int b  = l >> 4;            // local batch (pointwise) ; also k-chunk (frags)
  const int kg = b;                 // k-chunk index 0..3 for MFMA fragments
  const int ab = (l & 15) >> 2;     // batch of this lane's A-frag row
  const int atoff = l & 3;          // t-offset of this lane's A-frag row
  const int bc = blockIdx.x;        // 0..31 (chunk of 4 batches)
  const int n  = blockIdx.y;        // 0..99
  const int bga = bc*4 + ab;        // A-load global batch
  const int bgp = bc*4 + b;         // pointwise global batch

  __shared__ float hlds[4][16];

  // ---- Whh rows g, 16+g, 32+g in registers (fp32) ----
  const float* wh = Whh + ((size_t)n*48 + g)*GG;
  const float4 ur0 = *(const float4*)(wh+0),  ur1 = *(const float4*)(wh+4),
               ur2 = *(const float4*)(wh+8),  ur3 = *(const float4*)(wh+12);
  const float4 uz0 = *(const float4*)(wh+256),  uz1 = *(const float4*)(wh+260),
               uz2 = *(const float4*)(wh+264),  uz3 = *(const float4*)(wh+268);
  const float4 un0 = *(const float4*)(wh+512),  un1 = *(const float4*)(wh+516),
               un2 = *(const float4*)(wh+520),  un3 = *(const float4*)(wh+524);
  const float bir = bih[n*48 + g], biz = bih[n*48 + 16 + g], bin_ = bih[n*48 + 32 + g];
  const float bhr = bhh[n*48 + g], bhz = bhh[n*48 + 16 + g], bhn = bhh[n*48 + 32 + g];

  // ---- B fragments (Wih^T), bf16: lane holds B[k = kg*8+j][col = g] per gate-tile c ----
  short8 bw[3], bw2[3];
#pragma unroll
  for (int c = 0; c < 3; ++c) {
    const float* wp = Wih + ((size_t)n*48 + c*16 + g)*FF;
    float t0_[8], t1_[8];
#pragma unroll
    for (int j = 0; j < 8; ++j) t0_[j] = wp[kg*8 + j];             // k = 0..31 all < 35
#pragma unroll
    for (int j = 0; j < 8; ++j) {
      const int k2 = 32 + kg*8 + j;
      t1_[j] = (k2 < FF) ? wp[k2] : 0.0f;
    }
    union { short8 s; unsigned u[4]; } U, V;
#pragma unroll
    for (int jj = 0; jj < 4; ++jj) { U.u[jj] = bfp(t0_[2*jj], t0_[2*jj+1]);
                                     V.u[jj] = bfp(t1_[2*jj], t1_[2*jj+1]); }
    bw[c] = U.s; bw2[c] = V.s;
  }

  // ---- per-lane A-load metadata: row (ab, atoff), k = kg*8 + j ----
  int adelta[8]; unsigned amask = 0;
#pragma unroll
  for (int j = 0; j < 8; ++j) {
    const int f  = kg*8 + j;             // 0..31
    const int fi = (f * 586) >> 12;      // f / 7
    const int s  = f - fi*7;
    const int mo = (fi == 0) ? 0 : (fi == 1) ? -10 : (fi == 2) ? 1 : (fi == 3) ? 10 : -1;
    adelta[j] = mo*SS + s;
    const int m = n + mo;
    if (m >= 0 && m < NN) amask |= (1u << j);
  }
  const bool v2 = (kg == 0) && (n >= 1);  // frag2: k=32..34 -> offset -1, s=4..6

  // ---- initial prefetch (round 0: lane's row is timestep atoff) ----
  float xv[8], xv2[3];
  {
    const float* xq = x + ((size_t)bga*TT + atoff)*(NN*SS) + n*SS;
#pragma unroll
    for (int j = 0; j < 8; ++j) xv[j] = ((amask >> j) & 1u) ? xq[adelta[j]] : 0.0f;
#pragma unroll
    for (int j = 0; j < 3; ++j) xv2[j] = v2 ? xq[-3 + j] : 0.0f;
  }

  hlds[b][g] = 0.0f;
  float hown = 0.0f;

  const f32x4 z4 = {0.0f, 0.0f, 0.0f, 0.0f};

  for (int rd = 0; rd < TT/4; ++rd) {
    // build A fragments from prefetched values
    union { short8 s; unsigned u[4]; } A1, A2;
#pragma unroll
    for (int jj = 0; jj < 4; ++jj) A1.u[jj] = bfp(xv[2*jj], xv[2*jj+1]);
    A2.u[0] = bfp(xv2[0], xv2[1]); A2.u[1] = bfp(xv2[2], 0.0f); A2.u[2] = 0; A2.u[3] = 0;
    const short8 af1 = A1.s, af2 = A2.s;

    // prefetch next round (timestep = (rd+1)*4 + atoff)
    if (rd < TT/4 - 1) {
      const float* xq = x + ((size_t)bga*TT + (rd*4 + 4 + atoff))*(NN*SS) + n*SS;
#pragma unroll
      for (int j = 0; j < 8; ++j) xv[j] = ((amask >> j) & 1u) ? xq[adelta[j]] : 0.0f;
#pragma unroll
      for (int j = 0; j < 3; ++j) xv2[j] = v2 ? xq[-3 + j] : 0.0f;
    }

    // gi for 4 batches x 4 timesteps x 48 gates: C row = batch*4 + toff
    f32x4 c0 = __builtin_amdgcn_mfma_f32_16x16x32_bf16(af1, bw[0], z4, 0, 0, 0);
    c0 = __builtin_amdgcn_mfma_f32_16x16x32_bf16(af2, bw2[0], c0, 0, 0, 0);
    f32x4 c1 = __builtin_amdgcn_mfma_f32_16x16x32_bf16(af1, bw[1], z4, 0, 0, 0);
    c1 = __builtin_amdgcn_mfma_f32_16x16x32_bf16(af2, bw2[1], c1, 0, 0, 0);
    f32x4 c2 = __builtin_amdgcn_mfma_f32_16x16x32_bf16(af1, bw[2], z4, 0, 0, 0);
    c2 = __builtin_amdgcn_mfma_f32_16x16x32_bf16(af2, bw2[2], c2, 0, 0, 0);

    // 4 recurrent steps; lane holds (b = l>>4, g = l&15), gi at frag element toff
#pragma unroll
    for (int toff = 0; toff < 4; ++toff) {
      const float ir  = c0[toff] + bir;
      const float iz  = c1[toff] + biz;
      const float in_ = c2[toff] + bin_;
      const float4* hp = (const float4*)(&hlds[b][0]);
      const float4 h0 = hp[0], h1 = hp[1], h2 = hp[2], h3 = hp[3];
      float hr = bhr, hz = bhz, hn = bhn;
      DOT16(hr, ur0, ur1, ur2, ur3, h0, h1, h2, h3)
      DOT16(hz, uz0, uz1, uz2, uz3, h0, h1, h2, h3)
      DOT16(hn, un0, un1, un2, un3, h0, h1, h2, h3)
      const float r   = sigmoidf_(ir + hr);
      const float z   = sigmoidf_(iz + hz);
      const float nn2 = tanhf_(in_ + r * hn);
      const float hnew = nn2 + z * (hown - nn2);
      hlds[b][g] = hnew;
      hown = hnew;
    }
  }

  // ----- sc head: 16 -> 16 -> 16 -> 1 (wave-local, LDS exchange) -----
  {
    const float4* hp = (const float4*)(&hlds[b][0]);
    const float4 h0 = hp[0], h1 = hp[1], h2 = hp[2], h3 = hp[3];
    const float* w1 = sW1 + n*GG*GG + g;
    float a1 = sb1[n*GG + g];
    a1 += h0.x*w1[0*GG] + h0.y*w1[1*GG] + h0.z*w1[2*GG] + h0.w*w1[3*GG];
    a1 += h1.x*w1[4*GG] + h1.y*w1[5*GG] + h1.z*w1[6*GG] + h1.w*w1[7*GG];
    a1 += h2.x*w1[8*GG] + h2.y*w1[9*GG] + h2.z*w1[10*GG] + h2.w*w1[11*GG];
    a1 += h3.x*w1[12*GG] + h3.y*w1[13*GG] + h3.z*w1[14*GG] + h3.w*w1[15*GG];
    a1 = fmaxf(a1, 0.0f);
    hlds[b][g] = a1;
  }
  {
    const float4* hp = (const float4*)(&hlds[b][0]);
    const float4 h0 = hp[0], h1 = hp[1], h2 = hp[2], h3 = hp[3];
    const float* w2 = sW2 + n*GG*GG + g;
    float a2 = sb2[n*GG + g];
    a2 += h0.x*w2[0*GG] + h0.y*w2[1*GG] + h0.z*w2[2*GG] + h0.w*w2[3*GG];
    a2 += h1.x*w2[4*GG] + h1.y*w2[5*GG] + h1.z*w2[6*GG] + h1.w*w2[7*GG];
    a2 += h2.x*w2[8*GG] + h2.y*w2[9*GG] + h2.z*w2[10*GG] + h2.w*w2[11*GG];
    a2 += h3.x*w2[12*GG] + h3.y*w2[13*GG] + h3.z*w2[14*GG] + h3.w*w2[15*GG];
    a2 = fmaxf(a2, 0.0f);
    // q = sum_k a2[b][k] * sW3[n][k]  (reduce across the 16-lane group)
    float p = a2 * sW3[n*GG + g];
    p += __shfl_xor(p, 1);
    p += __shfl_xor(p, 2);
    p += __shfl_xor(p, 4);
    p += __shfl_xor(p, 8);
    if (g == 0) out[n * BB + bgp] += p + sb3[n];
  }
}

extern "C" void kernel_launch(void* const* d_in, const int* in_sizes, int n_in,
                              void* d_out, int out_size, void* d_ws, size_t ws_size,
                              hipStream_t stream) {
  const float* x     = (const float*)d_in[0];
  const float* lm_W1 = (const float*)d_in[1];
  const float* lm_b1 = (const float*)d_in[2];
  const float* lm_W2 = (const float*)d_in[3];
  const float* lm_b2 = (const float*)d_in[4];
  const float* lm_W3 = (const float*)d_in[5];
  const float* lm_b3 = (const float*)d_in[6];
  const float* gWih  = (const float*)d_in[7];
  const float* gWhh  = (const float*)d_in[8];
  const float* gbih  = (const float*)d_in[9];
  const float* gbhh  = (const float*)d_in[10];
  const float* sW1   = (const float*)d_in[11];
  const float* sb1   = (const float*)d_in[12];
  const float* sW2   = (const float*)d_in[13];
  const float* sb2   = (const float*)d_in[14];
  const float* sW3   = (const float*)d_in[15];
  const float* sb3   = (const float*)d_in[16];
  float* out = (float*)d_out;

  float* H1 = (float*)d_ws;                                       // 128*100*512 f32 = 26.2 MB
  float* H2 = (float*)((char*)d_ws + (size_t)BB * NN * 512 * 4);  // 128*100*256 f32 = 13.1 MB

  k_lm1<<<dim3(4, NN), 512, 0, stream>>>(x, lm_W1, lm_b1, H1);
  k_lm2<<<dim3(NN, 8), 256, 0, stream>>>(H1, lm_W2, lm_b2, H2);
  k_lm3<<<dim3(3200), 256, 0, stream>>>(H2, lm_W3, lm_b3, out);
  k_gru<<<dim3(32, NN), 64, 0, stream>>>(x, gWih, gWhh, gbih, gbhh,
                                         sW1, sb1, sW2, sb2, sW3, sb3, out);
}